// Round 11
// baseline (136.230 us; speedup 1.0000x reference)
//
#include <hip/hip_runtime.h>

// Problem constants (match reference)
#define N_ITEMS   64
#define CAPACITY  102.0f
#define N_PGD     120
#define ETA       0.1f

typedef float v2f __attribute__((ext_vector_type(2)));

// ---- DPP helpers: butterfly reductions over 8-lane groups ----------------
//   0xB1  = quad_perm [1,0,3,2]  -> lane ^ 1
//   0x4E  = quad_perm [2,3,0,1]  -> lane ^ 2
//   0x141 = row_half_mirror      -> lane ^ 7 within each 8-lane half
// All 8 lanes end bitwise-identical after the butterfly, so per-group
// decisions (bracket updates, lam) are uniform within the group.
template <int CTRL>
__device__ __forceinline__ float dpp_movf(float x) {
  return __builtin_bit_cast(
      float, __builtin_amdgcn_update_dpp(0, __builtin_bit_cast(int, x), CTRL,
                                         0xF, 0xF, true));
}

__device__ __forceinline__ float grp8_sum(float x) {
  x += dpp_movf<0xB1>(x);
  x += dpp_movf<0x4E>(x);
  x += dpp_movf<0x141>(x);
  return x;
}

__device__ __forceinline__ float grp8_max(float x) {
  x = fmaxf(x, dpp_movf<0xB1>(x));
  x = fmaxf(x, dpp_movf<0x4E>(x));
  x = fmaxf(x, dpp_movf<0x141>(x));
  return x;
}

__device__ __forceinline__ float clip01(float z) {
  return __builtin_amdgcn_fmed3f(z, 0.0f, 1.0f);  // single v_med3_f32
}

// False-position estimate from the bracket. Invariant: flo > 0 >= fhi
// (Illinois halving scales f-values by 0.5, preserving signs), so
// fhi - flo < 0 strictly -> no divide-by-zero/NaN; the med3 clamp at the
// call site absorbs any rounding excursion outside [lo, hi].
__device__ __forceinline__ float false_pos(float lo, float flo, float hi,
                                           float fhi) {
  const float t = fhi * __builtin_amdgcn_rcpf(fhi - flo);
  return fmaf(-t, hi - lo, hi);  // hi - fhi*(hi-lo)/(fhi-flo)
}

// 8 lanes per row, 8 items per lane, TWO independent rows per thread
// (in-thread software pipelining: at 1 wave/SIMD the second row's chains
// fill the first row's dependency stalls). 16384 rows -> 8192 groups x 8
// lanes = 65536 threads = 1024 waves. Weights are shared between rows.
__global__ __launch_bounds__(256, 1) void pgd_knapsack(
    const float* __restrict__ costs, const float* __restrict__ weights,
    float* __restrict__ out) {
  const int tid   = blockIdx.x * 256 + threadIdx.x;
  const int sub   = tid & 7;                 // lane within row-group
  const int grp   = tid >> 3;                // handles rows 2*grp, 2*grp+1
  const int baseA = grp * (2 * N_ITEMS) + sub * 8;
  const int baseB = baseA + N_ITEMS;

  v2f w[4];                       // shared by both rows
  v2f ecA[4], xA[4], yA[4];
  v2f ecB[4], xB[4], yB[4];

  float BA, BB;  // bracket half-widths: g(-B) = sum(w), g(+B) = 0
  float flo0;    // f(-B) = sum(w) - CAPACITY, exact, shared
  {
    const float4 w0 = *reinterpret_cast<const float4*>(weights + sub * 8);
    const float4 w1 = *reinterpret_cast<const float4*>(weights + sub * 8 + 4);
    w[0] = {w0.x, w0.y}; w[1] = {w0.z, w0.w};
    w[2] = {w1.x, w1.y}; w[3] = {w1.z, w1.w};

    const float4 a0 = *reinterpret_cast<const float4*>(costs + baseA);
    const float4 a1 = *reinterpret_cast<const float4*>(costs + baseA + 4);
    const float4 b0 = *reinterpret_cast<const float4*>(costs + baseB);
    const float4 b1 = *reinterpret_cast<const float4*>(costs + baseB + 4);
    const float ccA[8] = {a0.x, a0.y, a0.z, a0.w, a1.x, a1.y, a1.z, a1.w};
    const float ccB[8] = {b0.x, b0.y, b0.z, b0.w, b1.x, b1.y, b1.z, b1.w};
    float cabA = 0.0f, cabB = 0.0f;
#pragma unroll
    for (int p = 0; p < 4; ++p) {
      ecA[p] = (v2f){ETA * ccA[2 * p], ETA * ccA[2 * p + 1]};
      ecB[p] = (v2f){ETA * ccB[2 * p], ETA * ccB[2 * p + 1]};
      yA[p]  = (v2f){clip01(ccA[2 * p]), clip01(ccA[2 * p + 1])};
      yB[p]  = (v2f){clip01(ccB[2 * p]), clip01(ccB[2 * p + 1])};
      cabA = fmaxf(cabA, fmaxf(fabsf(ccA[2 * p]), fabsf(ccA[2 * p + 1])));
      cabB = fmaxf(cabB, fmaxf(fabsf(ccB[2 * p]), fabsf(ccB[2 * p + 1])));
    }
    cabA = grp8_max(cabA);
    cabB = grp8_max(cabB);
    // Every PGD iterate satisfies y_j in [-0.1 - eta*cab, 1 + eta*cab]
    // (since (1 - eta/||x||) * x_j in [-eta, 1]); with w_j >= 1 this makes
    // +-B a valid bracket: all coords clipped to 1 at -B, to 0 at +B.
    BA = fmaf(ETA, cabA, 1.1f) + 1e-3f;
    BB = fmaf(ETA, cabB, 1.1f) + 1e-3f;
    const v2f sw = (w[0] + w[1]) + (w[2] + w[3]);
    flo0 = grp8_sum(sw.x + sw.y) - CAPACITY;  // = 340 - 102, exact
  }
  const float fhi0 = -CAPACITY;  // f(+B) = 0 - CAPACITY, exact

  float lamA_est = 0.0f, lamB_est = 0.0f;  // warm starts across iterations

  // g(lam) - CAPACITY for one row (8 items/lane over the 8-lane group).
  auto eval_f = [&w](const v2f* __restrict__ y, float lam) -> float {
    const v2f nl = {-lam, -lam};
    const v2f z0 = __builtin_elementwise_fma(nl, w[0], y[0]);
    const v2f z1 = __builtin_elementwise_fma(nl, w[1], y[1]);
    const v2f z2 = __builtin_elementwise_fma(nl, w[2], y[2]);
    const v2f z3 = __builtin_elementwise_fma(nl, w[3], y[3]);
    const v2f t0 = {clip01(z0.x), clip01(z0.y)};
    const v2f t1 = {clip01(z1.x), clip01(z1.y)};
    const v2f t2 = {clip01(z2.x), clip01(z2.y)};
    const v2f t3 = {clip01(z3.x), clip01(z3.y)};
    v2f q0 = w[0] * t0;
    q0 = __builtin_elementwise_fma(w[1], t1, q0);
    v2f q1 = w[2] * t2;
    q1 = __builtin_elementwise_fma(w[3], t3, q1);
    const v2f q = q0 + q1;
    return grp8_sum(q.x + q.y) - CAPACITY;
  };

  // ---- dual-row projection: R10's proven solver, stages interleaved ------
  // Per row: warm probe + 2 Illinois false positions + exact final pick
  // (3 evals = verified accuracy floor, R8; no data-dependent freeze, R6).
  // Joint wave-uniform eval3 skip when every group's brackets (both rows)
  // are already < 1e-5 wide: skipping perturbs lam by <= 1e-5, one-shot.
  auto solve_project = [&]() {
    float loA = -BA, hiA = BA, floA = flo0, fhiA = fhi0;
    float loB = -BB, hiB = BB, floB = flo0, fhiB = fhi0;
    bool prevposA, prevposB;

    // stage 1: warm probes (A and B evals are independent -> dual chains)
    float lamA = __builtin_amdgcn_fmed3f(lamA_est, loA, hiA);
    float lamB = __builtin_amdgcn_fmed3f(lamB_est, loB, hiB);
    {
      const float fA = eval_f(yA, lamA);
      const float fB = eval_f(yB, lamB);
      const bool posA = fA > 0.0f;
      floA = posA ? fA : floA;
      loA  = posA ? lamA : loA;
      fhiA = posA ? fhiA : fA;
      hiA  = posA ? hiA : lamA;
      prevposA = posA;
      const bool posB = fB > 0.0f;
      floB = posB ? fB : floB;
      loB  = posB ? lamB : loB;
      fhiB = posB ? fhiB : fB;
      hiB  = posB ? hiB : lamB;
      prevposB = posB;
    }

    // stage 2: false position with Illinois halving
    {
      lamA = __builtin_amdgcn_fmed3f(false_pos(loA, floA, hiA, fhiA), loA, hiA);
      lamB = __builtin_amdgcn_fmed3f(false_pos(loB, floB, hiB, fhiB), loB, hiB);
      const float fA = eval_f(yA, lamA);
      const float fB = eval_f(yB, lamB);
      const bool posA = fA > 0.0f;
      const bool repA = (posA == prevposA);
      floA = posA ? fA : (repA ? 0.5f * floA : floA);
      loA  = posA ? lamA : loA;
      fhiA = posA ? (repA ? 0.5f * fhiA : fhiA) : fA;
      hiA  = posA ? hiA : lamA;
      prevposA = posA;
      const bool posB = fB > 0.0f;
      const bool repB = (posB == prevposB);
      floB = posB ? fB : (repB ? 0.5f * floB : floB);
      loB  = posB ? lamB : loB;
      fhiB = posB ? (repB ? 0.5f * fhiB : fhiB) : fB;
      hiB  = posB ? hiB : lamB;
      prevposB = posB;
    }

    // stage 3: identical Illinois step, jointly skipped only if the whole
    // wave's brackets (both rows) have collapsed below 1e-5.
    const bool tiny = ((hiA - loA) <= 1e-5f) && ((hiB - loB) <= 1e-5f);
    if (!__all(tiny)) {
      lamA = __builtin_amdgcn_fmed3f(false_pos(loA, floA, hiA, fhiA), loA, hiA);
      lamB = __builtin_amdgcn_fmed3f(false_pos(loB, floB, hiB, fhiB), loB, hiB);
      const float fA = eval_f(yA, lamA);
      const float fB = eval_f(yB, lamB);
      const bool posA = fA > 0.0f;
      const bool repA = (posA == prevposA);
      floA = posA ? fA : (repA ? 0.5f * floA : floA);
      loA  = posA ? lamA : loA;
      fhiA = posA ? (repA ? 0.5f * fhiA : fhiA) : fA;
      hiA  = posA ? hiA : lamA;
      const bool posB = fB > 0.0f;
      const bool repB = (posB == prevposB);
      floB = posB ? fB : (repB ? 0.5f * floB : floB);
      loB  = posB ? lamB : loB;
      fhiB = posB ? (repB ? 0.5f * fhiB : fhiB) : fB;
      hiB  = posB ? hiB : lamB;
    }

    // final derivative-free picks (no extra eval)
    lamA = __builtin_amdgcn_fmed3f(false_pos(loA, floA, hiA, fhiA), loA, hiA);
    lamB = __builtin_amdgcn_fmed3f(false_pos(loB, floB, hiB, fhiB), loB, hiB);
    lamA_est = lamA;
    lamB_est = lamB;
    const float luA = fmaxf(lamA, 0.0f);  // inactive constraint -> 0
    const float luB = fmaxf(lamB, 0.0f);

    const v2f nlA = {-luA, -luA};
    const v2f nlB = {-luB, -luB};
#pragma unroll
    for (int p = 0; p < 4; ++p) {
      const v2f zA = __builtin_elementwise_fma(nlA, w[p], yA[p]);
      const v2f zB = __builtin_elementwise_fma(nlB, w[p], yB[p]);
      xA[p] = (v2f){clip01(zA.x), clip01(zA.y)};
      xB[p] = (v2f){clip01(zB.x), clip01(zB.y)};
    }
  };

  // Iteration 0 peeled: y is already clip01(c).
  solve_project();

#pragma unroll 1
  for (int it = 1; it <= N_PGD; ++it) {
    // y = (1 - eta/||x||)*x + eta*c, both rows (independent reduce chains)
    v2f aA = xA[0] * xA[0];
    aA = __builtin_elementwise_fma(xA[1], xA[1], aA);
    v2f bA = xA[2] * xA[2];
    bA = __builtin_elementwise_fma(xA[3], xA[3], bA);
    v2f aB = xB[0] * xB[0];
    aB = __builtin_elementwise_fma(xB[1], xB[1], aB);
    v2f bB = xB[2] * xB[2];
    bB = __builtin_elementwise_fma(xB[3], xB[3], bB);
    const v2f abA = aA + bA;
    const v2f abB = aB + bB;
    const float s2A = grp8_sum(abA.x + abA.y);
    const float s2B = grp8_sum(abB.x + abB.y);
    const float sA  = 1.0f - ETA * __builtin_amdgcn_rsqf(s2A + 1e-12f);
    const float sB  = 1.0f - ETA * __builtin_amdgcn_rsqf(s2B + 1e-12f);
    const v2f svA = {sA, sA};
    const v2f svB = {sB, sB};
#pragma unroll
    for (int p = 0; p < 4; ++p) {
      yA[p] = __builtin_elementwise_fma(svA, xA[p], ecA[p]);
      yB[p] = __builtin_elementwise_fma(svB, xB[p], ecB[p]);
    }

    solve_project();
  }

  *reinterpret_cast<float4*>(out + baseA) =
      make_float4(xA[0].x, xA[0].y, xA[1].x, xA[1].y);
  *reinterpret_cast<float4*>(out + baseA + 4) =
      make_float4(xA[2].x, xA[2].y, xA[3].x, xA[3].y);
  *reinterpret_cast<float4*>(out + baseB) =
      make_float4(xB[0].x, xB[0].y, xB[1].x, xB[1].y);
  *reinterpret_cast<float4*>(out + baseB + 4) =
      make_float4(xB[2].x, xB[2].y, xB[3].x, xB[3].y);
}

extern "C" void kernel_launch(void* const* d_in, const int* in_sizes, int n_in,
                              void* d_out, int out_size, void* d_ws, size_t ws_size,
                              hipStream_t stream) {
  const float* costs   = (const float*)d_in[0];
  const float* weights = (const float*)d_in[1];
  float* out           = (float*)d_out;

  const int n_rows  = in_sizes[0] / N_ITEMS;  // 16384
  const int threads = (n_rows / 2) * 8;       // 8 lanes per 2-row group
  dim3 block(256);
  dim3 grid(threads / 256);
  pgd_knapsack<<<grid, block, 0, stream>>>(costs, weights, out);
}

// Round 12
// 114.359 us; speedup vs baseline: 1.1912x; 1.1912x over previous
//
#include <hip/hip_runtime.h>

// Problem constants (match reference)
#define N_ITEMS   64
#define CAPACITY  102.0f
#define N_PGD     120
#define ETA       0.1f

typedef float v2f __attribute__((ext_vector_type(2)));

// ---- DPP helpers: butterfly reductions over 4-lane quads ------------------
//   0xB1 = quad_perm [1,0,3,2] -> lane ^ 1
//   0x4E = quad_perm [2,3,0,1] -> lane ^ 2
// Both are quad-local, so a 4-lane problem-group never leaks into neighbors.
// All 4 lanes end bitwise-identical after the butterfly, so per-group
// decisions (bracket updates, lam) are uniform within the group.
template <int CTRL>
__device__ __forceinline__ float dpp_movf(float x) {
  return __builtin_bit_cast(
      float, __builtin_amdgcn_update_dpp(0, __builtin_bit_cast(int, x), CTRL,
                                         0xF, 0xF, true));
}

__device__ __forceinline__ float grp4_sum(float x) {
  x += dpp_movf<0xB1>(x);
  x += dpp_movf<0x4E>(x);
  return x;
}

__device__ __forceinline__ float grp4_max(float x) {
  x = fmaxf(x, dpp_movf<0xB1>(x));
  x = fmaxf(x, dpp_movf<0x4E>(x));
  return x;
}

__device__ __forceinline__ float clip01(float z) {
  return __builtin_amdgcn_fmed3f(z, 0.0f, 1.0f);  // single v_med3_f32
}

// 4 lanes per row, 16 items per lane. 16384 rows -> 65536 threads
// (1024 waves = 1 wave/SIMD). R10-proven structure; R12 adds dual-speculated
// false position (bitwise-identical lam sequence, shorter critical path).
__global__ __launch_bounds__(256, 1) void pgd_knapsack(
    const float* __restrict__ costs, const float* __restrict__ weights,
    float* __restrict__ out) {
  const int tid  = blockIdx.x * 256 + threadIdx.x;
  const int sub  = tid & 3;                 // lane within row-group
  const int base = (tid >> 2) * N_ITEMS + sub * 16;

  v2f w[8], ec[8], x[8], y[8];

  float B;     // bracket half-width: g(-B) = sum(w), g(+B) = 0 by construction
  float flo0;  // f(-B) = sum(w) - CAPACITY, exact, no eval needed
  {
    float cab = 0.0f;
#pragma unroll
    for (int u = 0; u < 4; ++u) {
      const float4 cq = *reinterpret_cast<const float4*>(costs + base + 4 * u);
      const float4 wq =
          *reinterpret_cast<const float4*>(weights + sub * 16 + 4 * u);
      w[2 * u]      = (v2f){wq.x, wq.y};
      w[2 * u + 1]  = (v2f){wq.z, wq.w};
      ec[2 * u]     = (v2f){ETA * cq.x, ETA * cq.y};
      ec[2 * u + 1] = (v2f){ETA * cq.z, ETA * cq.w};
      y[2 * u]      = (v2f){clip01(cq.x), clip01(cq.y)};
      y[2 * u + 1]  = (v2f){clip01(cq.z), clip01(cq.w)};
      cab = fmaxf(cab, fmaxf(fmaxf(fabsf(cq.x), fabsf(cq.y)),
                             fmaxf(fabsf(cq.z), fabsf(cq.w))));
    }
    cab = grp4_max(cab);
    // Every PGD iterate satisfies y_j in [-0.1 - eta*cab, 1 + eta*cab]
    // (since (1 - eta/||x||) * x_j in [-eta, 1]); with w_j >= 1 this makes
    // +-B a valid bracket: all coords clipped to 1 at -B, to 0 at +B.
    B = fmaf(ETA, cab, 1.1f) + 1e-3f;
    v2f sw = (w[0] + w[1]) + (w[2] + w[3]);
    sw = sw + ((w[4] + w[5]) + (w[6] + w[7]));
    flo0 = grp4_sum(sw.x + sw.y) - CAPACITY;  // = 340 - 102, exact
  }
  const float fhi0 = -CAPACITY;  // f(+B) = 0 - CAPACITY, exact

  float lam_est = 0.0f;  // unclamped root estimate, warm start across iters

  // g(lam) - CAPACITY over the 4-lane group (16 items/lane, 4 indep chains).
  auto eval_f = [&](float lam) -> float {
    const v2f nl = {-lam, -lam};
    v2f q[4];
#pragma unroll
    for (int p = 0; p < 4; ++p) {
      const v2f z0 = __builtin_elementwise_fma(nl, w[2 * p], y[2 * p]);
      const v2f z1 = __builtin_elementwise_fma(nl, w[2 * p + 1], y[2 * p + 1]);
      const v2f t0 = {clip01(z0.x), clip01(z0.y)};
      const v2f t1 = {clip01(z1.x), clip01(z1.y)};
      const v2f qq = w[2 * p] * t0;
      q[p] = __builtin_elementwise_fma(w[2 * p + 1], t1, qq);
    }
    const v2f qs = (q[0] + q[1]) + (q[2] + q[3]);
    return grp4_sum(qs.x + qs.y) - CAPACITY;
  };

  // ---- multiplier root-find on [-B, +B] + epilogue x = clip(y - lam*w) ----
  // R7/R10-proven solver: warm probe + 2 Illinois false positions + exact
  // final pick (3 evals = verified accuracy floor, R8; no data-dependent
  // freeze, R6; wave-uniform eval3 skip at bracket width <= 1e-5, R10).
  // Each stage uses DUAL-SPECULATED false position: both candidate next
  // points (for f>0 and f<=0) are computed concurrently the moment f lands
  // -- the rcp chain no longer waits on the bracket cndmasks. The selected
  // lam is bitwise-identical to the sequential update-then-false_pos; the
  // untaken side may be inf/NaN (den==0) and is discarded by the select.
  // Taken-side denominators are strictly negative: flo > 0 >= fhi invariant
  // (Illinois halving preserves signs).
  auto solve_project = [&]() {
    float lo = -B, hi = B, flo = flo0, fhi = fhi0;
    bool prevpos;

    // stage 1: warm probe at the previous iteration's root estimate
    // (no Illinois adjustment on the first update)
    float lam = __builtin_amdgcn_fmed3f(lam_est, lo, hi);
    float lam2;
    {
      const float f = eval_f(lam);
      const float fp_pos =
          fmaf(-(fhi * __builtin_amdgcn_rcpf(fhi - f)), hi - lam, hi);
      const float fp_neg =
          fmaf(-(f * __builtin_amdgcn_rcpf(f - flo)), lam - lo, lam);
      const bool pos = f > 0.0f;
      flo = pos ? f : flo;
      lo  = pos ? lam : lo;
      fhi = pos ? fhi : f;
      hi  = pos ? hi : lam;
      prevpos = pos;
      lam2 = __builtin_amdgcn_fmed3f(pos ? fp_pos : fp_neg, lo, hi);
    }

    // stage 2: false position, Illinois halving (adj depends only on
    // prevpos -- computed before f arrives, off the critical path)
    float lam3;
    {
      const float fhi_a = prevpos ? 0.5f * fhi : fhi;
      const float flo_a = prevpos ? flo : 0.5f * flo;
      const float f = eval_f(lam2);
      const float fp_pos =
          fmaf(-(fhi_a * __builtin_amdgcn_rcpf(fhi_a - f)), hi - lam2, hi);
      const float fp_neg =
          fmaf(-(f * __builtin_amdgcn_rcpf(f - flo_a)), lam2 - lo, lam2);
      const bool pos = f > 0.0f;
      flo = pos ? f : flo_a;
      lo  = pos ? lam2 : lo;
      fhi = pos ? fhi_a : f;
      hi  = pos ? hi : lam2;
      prevpos = pos;
      lam3 = __builtin_amdgcn_fmed3f(pos ? fp_pos : fp_neg, lo, hi);
    }

    // stage 3: identical Illinois step, skipped only if the whole wave's
    // brackets have already collapsed below 1e-5 (skip perturbs lam by
    // <= 1e-5, one-shot, non-accumulating).
    float pick;
    const bool tiny = (hi - lo) <= 1e-5f;
    if (!__all(tiny)) {
      const float fhi_a = prevpos ? 0.5f * fhi : fhi;
      const float flo_a = prevpos ? flo : 0.5f * flo;
      const float f = eval_f(lam3);
      const float fp_pos =
          fmaf(-(fhi_a * __builtin_amdgcn_rcpf(fhi_a - f)), hi - lam3, hi);
      const float fp_neg =
          fmaf(-(f * __builtin_amdgcn_rcpf(f - flo_a)), lam3 - lo, lam3);
      const bool pos = f > 0.0f;
      flo = pos ? f : flo_a;
      lo  = pos ? lam3 : lo;
      fhi = pos ? fhi_a : f;
      hi  = pos ? hi : lam3;
      // final derivative-free pick (no extra eval)
      pick = __builtin_amdgcn_fmed3f(pos ? fp_pos : fp_neg, lo, hi);
    } else {
      pick = lam3;  // same value the sequential code would produce
    }

    lam_est = pick;
    const float lam_use = fmaxf(pick, 0.0f);  // inactive constraint -> 0

    const v2f nl = {-lam_use, -lam_use};
#pragma unroll
    for (int p = 0; p < 8; ++p) {
      const v2f z = __builtin_elementwise_fma(nl, w[p], y[p]);
      x[p] = (v2f){clip01(z.x), clip01(z.y)};
    }
  };

  // Iteration 0 peeled: y is already clip01(c).
  solve_project();

#pragma unroll 2
  for (int it = 1; it <= N_PGD; ++it) {
    // y = x + eta*(c - x/||x||) = (1 - eta/||x||)*x + eta*c
    v2f a = x[0] * x[0];
    a = __builtin_elementwise_fma(x[1], x[1], a);
    v2f b = x[2] * x[2];
    b = __builtin_elementwise_fma(x[3], x[3], b);
    v2f c2 = x[4] * x[4];
    c2 = __builtin_elementwise_fma(x[5], x[5], c2);
    v2f d = x[6] * x[6];
    d = __builtin_elementwise_fma(x[7], x[7], d);
    const v2f ab = (a + b) + (c2 + d);
    const float s2  = grp4_sum(ab.x + ab.y);
    const float inv = __builtin_amdgcn_rsqf(s2 + 1e-12f);
    const float s   = 1.0f - ETA * inv;
    const v2f sv = {s, s};
#pragma unroll
    for (int p = 0; p < 8; ++p)
      y[p] = __builtin_elementwise_fma(sv, x[p], ec[p]);

    solve_project();
  }

#pragma unroll
  for (int u = 0; u < 4; ++u) {
    *reinterpret_cast<float4*>(out + base + 4 * u) =
        make_float4(x[2 * u].x, x[2 * u].y, x[2 * u + 1].x, x[2 * u + 1].y);
  }
}

extern "C" void kernel_launch(void* const* d_in, const int* in_sizes, int n_in,
                              void* d_out, int out_size, void* d_ws, size_t ws_size,
                              hipStream_t stream) {
  const float* costs   = (const float*)d_in[0];
  const float* weights = (const float*)d_in[1];
  float* out           = (float*)d_out;

  const int n_rows  = in_sizes[0] / N_ITEMS;  // 16384
  const int threads = n_rows * 4;             // 4 lanes per row
  dim3 block(256);
  dim3 grid(threads / 256);
  pgd_knapsack<<<grid, block, 0, stream>>>(costs, weights, out);
}

// Round 13
// 112.835 us; speedup vs baseline: 1.2073x; 1.0135x over previous
//
#include <hip/hip_runtime.h>

// Problem constants (match reference)
#define N_ITEMS   64
#define CAPACITY  102.0f
#define N_PGD     120
#define ETA       0.1f

typedef float v2f __attribute__((ext_vector_type(2)));

// ---- DPP helpers: butterfly reductions over 4-lane quads ------------------
//   0xB1 = quad_perm [1,0,3,2] -> lane ^ 1
//   0x4E = quad_perm [2,3,0,1] -> lane ^ 2
// Both are quad-local, so a 4-lane problem-group never leaks into neighbors.
// All 4 lanes end bitwise-identical after the butterfly, so per-group
// decisions (bracket updates, lam) are uniform within the group.
template <int CTRL>
__device__ __forceinline__ float dpp_movf(float x) {
  return __builtin_bit_cast(
      float, __builtin_amdgcn_update_dpp(0, __builtin_bit_cast(int, x), CTRL,
                                         0xF, 0xF, true));
}

__device__ __forceinline__ float grp4_sum(float x) {
  x += dpp_movf<0xB1>(x);
  x += dpp_movf<0x4E>(x);
  return x;
}

__device__ __forceinline__ float grp4_max(float x) {
  x = fmaxf(x, dpp_movf<0xB1>(x));
  x = fmaxf(x, dpp_movf<0x4E>(x));
  return x;
}

__device__ __forceinline__ float clip01(float z) {
  return __builtin_amdgcn_fmed3f(z, 0.0f, 1.0f);  // single v_med3_f32
}

// False-position estimate from the bracket. Invariant: flo > 0 >= fhi
// (Illinois halving scales f-values by 0.5, preserving signs), so
// fhi - flo < 0 strictly -> no divide-by-zero/NaN; the med3 clamp at the
// call site absorbs any rounding excursion outside [lo, hi].
// Single rcp per pick: rcp is a quarter-rate trans op -- R12's dual
// speculation added 3 extra rcps/iter and raised busy time; reverted.
__device__ __forceinline__ float false_pos(float lo, float flo, float hi,
                                           float fhi) {
  const float t = fhi * __builtin_amdgcn_rcpf(fhi - flo);
  return fmaf(-t, hi - lo, hi);  // hi - fhi*(hi-lo)/(fhi-flo)
}

// 4 lanes per row, 16 items per lane. 16384 rows -> 65536 threads
// (1024 waves = 1 wave/SIMD). R10-proven structure; Illinois halvings are
// precomputed off the critical path (the only surviving piece of R12).
__global__ __launch_bounds__(256, 1) void pgd_knapsack(
    const float* __restrict__ costs, const float* __restrict__ weights,
    float* __restrict__ out) {
  const int tid  = blockIdx.x * 256 + threadIdx.x;
  const int sub  = tid & 3;                 // lane within row-group
  const int base = (tid >> 2) * N_ITEMS + sub * 16;

  v2f w[8], ec[8], x[8], y[8];

  float B;     // bracket half-width: g(-B) = sum(w), g(+B) = 0 by construction
  float flo0;  // f(-B) = sum(w) - CAPACITY, exact, no eval needed
  {
    float cab = 0.0f;
#pragma unroll
    for (int u = 0; u < 4; ++u) {
      const float4 cq = *reinterpret_cast<const float4*>(costs + base + 4 * u);
      const float4 wq =
          *reinterpret_cast<const float4*>(weights + sub * 16 + 4 * u);
      w[2 * u]      = (v2f){wq.x, wq.y};
      w[2 * u + 1]  = (v2f){wq.z, wq.w};
      ec[2 * u]     = (v2f){ETA * cq.x, ETA * cq.y};
      ec[2 * u + 1] = (v2f){ETA * cq.z, ETA * cq.w};
      y[2 * u]      = (v2f){clip01(cq.x), clip01(cq.y)};
      y[2 * u + 1]  = (v2f){clip01(cq.z), clip01(cq.w)};
      cab = fmaxf(cab, fmaxf(fmaxf(fabsf(cq.x), fabsf(cq.y)),
                             fmaxf(fabsf(cq.z), fabsf(cq.w))));
    }
    cab = grp4_max(cab);
    // Every PGD iterate satisfies y_j in [-0.1 - eta*cab, 1 + eta*cab]
    // (since (1 - eta/||x||) * x_j in [-eta, 1]); with w_j >= 1 this makes
    // +-B a valid bracket: all coords clipped to 1 at -B, to 0 at +B.
    B = fmaf(ETA, cab, 1.1f) + 1e-3f;
    v2f sw = (w[0] + w[1]) + (w[2] + w[3]);
    sw = sw + ((w[4] + w[5]) + (w[6] + w[7]));
    flo0 = grp4_sum(sw.x + sw.y) - CAPACITY;  // = 340 - 102, exact
  }
  const float fhi0 = -CAPACITY;  // f(+B) = 0 - CAPACITY, exact

  float lam_est = 0.0f;  // unclamped root estimate, warm start across iters

  // g(lam) - CAPACITY over the 4-lane group (16 items/lane, 4 indep chains).
  auto eval_f = [&](float lam) -> float {
    const v2f nl = {-lam, -lam};
    v2f q[4];
#pragma unroll
    for (int p = 0; p < 4; ++p) {
      const v2f z0 = __builtin_elementwise_fma(nl, w[2 * p], y[2 * p]);
      const v2f z1 = __builtin_elementwise_fma(nl, w[2 * p + 1], y[2 * p + 1]);
      const v2f t0 = {clip01(z0.x), clip01(z0.y)};
      const v2f t1 = {clip01(z1.x), clip01(z1.y)};
      const v2f qq = w[2 * p] * t0;
      q[p] = __builtin_elementwise_fma(w[2 * p + 1], t1, qq);
    }
    const v2f qs = (q[0] + q[1]) + (q[2] + q[3]);
    return grp4_sum(qs.x + qs.y) - CAPACITY;
  };

  // ---- multiplier root-find on [-B, +B] + epilogue x = clip(y - lam*w) ----
  // R7/R10-proven solver: warm probe + 2 Illinois false positions + exact
  // final pick (3 evals = verified accuracy floor, R8; no data-dependent
  // freeze, R6; wave-uniform eval3 skip at bracket width <= 1e-5, R10).
  // Illinois halvings (0.5*flo / 0.5*fhi, selected by prevpos) are computed
  // BEFORE f lands -- off the critical path; bracket update itself is the
  // R10 sequential form (single rcp per pick).
  auto solve_project = [&]() {
    float lo = -B, hi = B, flo = flo0, fhi = fhi0;
    bool prevpos;

    // eval 1: warm probe. lam_est is always inside [-B, B]: it is either 0
    // (first iteration) or a med3 clamp into a sub-bracket of [-B, B], and
    // B is a per-row constant -- so no clamp is needed here.
    float lam = lam_est;
    {
      const float f = eval_f(lam);
      const bool pos = f > 0.0f;
      flo = pos ? f : flo;
      lo  = pos ? lam : lo;
      fhi = pos ? fhi : f;
      hi  = pos ? hi : lam;
      prevpos = pos;
    }

    // eval 2: false position with Illinois halving (halved values selected
    // by prevpos, computed before f arrives)
    {
      lam = __builtin_amdgcn_fmed3f(false_pos(lo, flo, hi, fhi), lo, hi);
      const float fhi_a = prevpos ? 0.5f * fhi : fhi;  // off critical path
      const float flo_a = prevpos ? flo : 0.5f * flo;
      const float f = eval_f(lam);
      const bool pos = f > 0.0f;
      flo = pos ? f : flo_a;
      lo  = pos ? lam : lo;
      fhi = pos ? fhi_a : f;
      hi  = pos ? hi : lam;
      prevpos = pos;
    }

    // eval 3: identical Illinois step, skipped only if the whole wave's
    // brackets have already collapsed below 1e-5 (skip perturbs lam by
    // <= 1e-5, one-shot, non-accumulating).
    const bool tiny = (hi - lo) <= 1e-5f;
    if (!__all(tiny)) {
      lam = __builtin_amdgcn_fmed3f(false_pos(lo, flo, hi, fhi), lo, hi);
      const float fhi_a = prevpos ? 0.5f * fhi : fhi;
      const float flo_a = prevpos ? flo : 0.5f * flo;
      const float f = eval_f(lam);
      const bool pos = f > 0.0f;
      flo = pos ? f : flo_a;
      lo  = pos ? lam : lo;
      fhi = pos ? fhi_a : f;
      hi  = pos ? hi : lam;
    }

    // final derivative-free pick (no extra eval)
    const float pick =
        __builtin_amdgcn_fmed3f(false_pos(lo, flo, hi, fhi), lo, hi);
    lam_est = pick;
    const float lam_use = fmaxf(pick, 0.0f);  // inactive constraint -> 0

    const v2f nl = {-lam_use, -lam_use};
#pragma unroll
    for (int p = 0; p < 8; ++p) {
      const v2f z = __builtin_elementwise_fma(nl, w[p], y[p]);
      x[p] = (v2f){clip01(z.x), clip01(z.y)};
    }
  };

  // Iteration 0 peeled: y is already clip01(c).
  solve_project();

#pragma unroll 2
  for (int it = 1; it <= N_PGD; ++it) {
    // y = x + eta*(c - x/||x||) = (1 - eta/||x||)*x + eta*c
    v2f a = x[0] * x[0];
    a = __builtin_elementwise_fma(x[1], x[1], a);
    v2f b = x[2] * x[2];
    b = __builtin_elementwise_fma(x[3], x[3], b);
    v2f c2 = x[4] * x[4];
    c2 = __builtin_elementwise_fma(x[5], x[5], c2);
    v2f d = x[6] * x[6];
    d = __builtin_elementwise_fma(x[7], x[7], d);
    const v2f ab = (a + b) + (c2 + d);
    const float s2  = grp4_sum(ab.x + ab.y);
    const float inv = __builtin_amdgcn_rsqf(s2 + 1e-12f);
    const float s   = 1.0f - ETA * inv;
    const v2f sv = {s, s};
#pragma unroll
    for (int p = 0; p < 8; ++p)
      y[p] = __builtin_elementwise_fma(sv, x[p], ec[p]);

    solve_project();
  }

#pragma unroll
  for (int u = 0; u < 4; ++u) {
    *reinterpret_cast<float4*>(out + base + 4 * u) =
        make_float4(x[2 * u].x, x[2 * u].y, x[2 * u + 1].x, x[2 * u + 1].y);
  }
}

extern "C" void kernel_launch(void* const* d_in, const int* in_sizes, int n_in,
                              void* d_out, int out_size, void* d_ws, size_t ws_size,
                              hipStream_t stream) {
  const float* costs   = (const float*)d_in[0];
  const float* weights = (const float*)d_in[1];
  float* out           = (float*)d_out;

  const int n_rows  = in_sizes[0] / N_ITEMS;  // 16384
  const int threads = n_rows * 4;             // 4 lanes per row
  dim3 block(256);
  dim3 grid(threads / 256);
  pgd_knapsack<<<grid, block, 0, stream>>>(costs, weights, out);
}